// Round 7
// baseline (1210.156 us; speedup 1.0000x reference)
//
#include <hip/hip_runtime.h>
#include <math.h>

#define N_NODES    100000
#define N_EDGES    3200000
#define N_FEAT     128
#define N_CLASSES  16
#define NUM_GRAPHS 512
#define NB         782          // bins of 128 nodes: bin = dst>>7 (782*128 = 100096)
#define NBLK_A     1024         // blocks in binning passes
#define EPB        3125         // edges per block: 1024*3125 = 3.2M exactly

// ---------- pass A0: per-block coarse histogram ----------

__global__ void binhist_kernel(const int* __restrict__ dst, int* __restrict__ hist) {
    __shared__ int h[NB];
    int t = threadIdx.x;
    for (int i = t; i < NB; i += 256) h[i] = 0;
    __syncthreads();
    int base = blockIdx.x * EPB;
    for (int e = base + t; e < base + EPB; e += 256) atomicAdd(&h[dst[e] >> 7], 1);
    __syncthreads();
    for (int i = t; i < NB; i += 256) hist[blockIdx.x * NB + i] = h[i];
}

// ---------- per-bin scan over blocks -> offs[bin][block], total[bin] ----------

__global__ void offs_scan_kernel(const int* __restrict__ hist, int* __restrict__ offs,
                                 int* __restrict__ total) {
    __shared__ int v[1024];
    int b = blockIdx.x, t = threadIdx.x;   // 1024 threads
    int x = hist[t * NB + b];
    v[t] = x;
    __syncthreads();
    for (int off = 1; off < 1024; off <<= 1) {
        int a = (t >= off) ? v[t - off] : 0;
        __syncthreads();
        v[t] += a;
        __syncthreads();
    }
    offs[b * NBLK_A + t] = v[t] - x;
    if (t == 1023) total[b] = v[1023];
}

// ---------- scan of bin totals -> binbase ----------

__global__ void total_scan_kernel(const int* __restrict__ total, int* __restrict__ binbase) {
    __shared__ int v[1024];
    int t = threadIdx.x;
    int x = (t < NB) ? total[t] : 0;
    v[t] = x;
    __syncthreads();
    for (int off = 1; off < 1024; off <<= 1) {
        int a = (t >= off) ? v[t - off] : 0;
        __syncthreads();
        v[t] += a;
        __syncthreads();
    }
    if (t < NB) binbase[t] = v[t] - x;
}

// ---------- pass A1: local counting sort by bin, coalesced scatter ----------

__global__ void binscatter_kernel(const int* __restrict__ src, const int* __restrict__ dst,
                                  const int* __restrict__ offs, const int* __restrict__ binbase,
                                  unsigned int* __restrict__ bins) {
    __shared__ int h[NB];                    // hist -> cursor (3.1 KB)
    __shared__ int lstart[NB];               // 3.1 KB
    __shared__ int gstart[NB];               // 3.1 KB
    __shared__ int sv[256];                  // 1 KB
    __shared__ unsigned int outp[EPB];       // 12.5 KB
    __shared__ unsigned short binof[EPB];    // 6.25 KB
    int t = threadIdx.x, blk = blockIdx.x;
    for (int i = t; i < NB; i += 256) h[i] = 0;
    __syncthreads();
    int base = blk * EPB;
    for (int e = base + t; e < base + EPB; e += 256) atomicAdd(&h[dst[e] >> 7], 1);
    __syncthreads();
    // exclusive scan of h[0..NB) : 4 bins per thread (NB <= 1024)
    int b0 = 4 * t;
    int l0 = (b0 + 0 < NB) ? h[b0 + 0] : 0;
    int l1 = (b0 + 1 < NB) ? h[b0 + 1] : 0;
    int l2 = (b0 + 2 < NB) ? h[b0 + 2] : 0;
    int l3 = (b0 + 3 < NB) ? h[b0 + 3] : 0;
    int tsum = l0 + l1 + l2 + l3;
    sv[t] = tsum;
    __syncthreads();
    for (int off = 1; off < 256; off <<= 1) {
        int a = (t >= off) ? sv[t - off] : 0;
        __syncthreads();
        sv[t] += a;
        __syncthreads();
    }
    int ex = sv[t] - tsum;
    if (b0 + 0 < NB) lstart[b0 + 0] = ex;
    if (b0 + 1 < NB) lstart[b0 + 1] = ex + l0;
    if (b0 + 2 < NB) lstart[b0 + 2] = ex + l0 + l1;
    if (b0 + 3 < NB) lstart[b0 + 3] = ex + l0 + l1 + l2;
    __syncthreads();
    for (int i = t; i < NB; i += 256) {
        gstart[i] = offs[i * NBLK_A + blk] + binbase[i];
        h[i] = lstart[i];                    // cursor
    }
    __syncthreads();
    for (int e = base + t; e < base + EPB; e += 256) {
        int s = src[e], d = dst[e];
        int b = d >> 7;
        int pos = atomicAdd(&h[b], 1);
        outp[pos] = (unsigned int)s | ((unsigned int)(d & 127) << 17);
        binof[pos] = (unsigned short)b;
    }
    __syncthreads();
    for (int i = t; i < EPB; i += 256) {
        int b = binof[i];
        bins[gstart[b] + (i - lstart[b])] = outp[i];
    }
}

// ---------- per-bin node histogram -> deg ----------

__global__ void bindeg_kernel(const unsigned int* __restrict__ bins,
                              const int* __restrict__ binbase, const int* __restrict__ total,
                              int* __restrict__ deg) {
    __shared__ int h[128];
    int b = blockIdx.x, t = threadIdx.x;
    if (t < 128) h[t] = 0;
    __syncthreads();
    int base = binbase[b], cnt = total[b];
    for (int i = t; i < cnt; i += 256) atomicAdd(&h[(bins[base + i] >> 17) & 127], 1);
    __syncthreads();
    if (t < 128) {
        int node = b * 128 + t;
        if (node < N_NODES) deg[node] = h[t];
    }
}

__global__ void finalize_dinv_kernel(const int* __restrict__ deg, float* __restrict__ dinv) {
    int i = blockIdx.x * blockDim.x + threadIdx.x;
    if (i < N_NODES) dinv[i] = rsqrtf((float)(deg[i] + 1));
}

// ---------- y = x @ W (float4-vectorized staging) ----------

__global__ void xw_kernel(const float* __restrict__ x, const float* __restrict__ W,
                          float* __restrict__ y) {
    __shared__ __align__(16) float sW[N_FEAT * N_CLASSES];   // 8 KB
    __shared__ __align__(16) float sx[16][132];              // padded: +4 kills 4-way conflict
    int t = threadIdx.x;
    for (int i = t; i < (N_FEAT * N_CLASSES) / 4; i += 256)
        *(float4*)&sW[i * 4] = *(const float4*)&W[i * 4];
    int row0 = blockIdx.x * 16;
    for (int i = t; i < 16 * 32; i += 256) {
        int r = i >> 5, q = i & 31;
        int rr = row0 + r;
        float4 v = make_float4(0.f, 0.f, 0.f, 0.f);
        if (rr < N_NODES) v = *(const float4*)&x[(long long)rr * N_FEAT + q * 4];
        *(float4*)&sx[r][q * 4] = v;
    }
    __syncthreads();
    int r = t >> 4, c = t & 15;
    float acc = 0.0f;
#pragma unroll 8
    for (int k = 0; k < N_FEAT; ++k) acc += sx[r][k] * sW[k * N_CLASSES + c];
    int rr = row0 + r;
    if (rr < N_NODES) y[rr * N_CLASSES + c] = acc;
}

// ---------- bin-major gather hop: edge-parallel, LDS accumulate ----------

__global__ void hopbin_kernel(const unsigned int* __restrict__ bins,
                              const int* __restrict__ binbase, const int* __restrict__ total,
                              const float* __restrict__ dinv,
                              const float* __restrict__ A, float* __restrict__ B) {
    __shared__ float acc[128 * 17];   // 8.7 KB, pad 17 vs bank conflicts
    int b = blockIdx.x, t = threadIdx.x;
    for (int i = t; i < 128 * 17; i += 256) acc[i] = 0.0f;
    __syncthreads();
    int base = binbase[b], cnt = total[b];
    int c = t & 15, eg = t >> 4;       // 16 edge-slots x 16 channels
#pragma unroll 4
    for (int i = eg; i < cnt; i += 16) {
        unsigned int p = bins[base + i];
        int s  = (int)(p & 0x1FFFF);
        int dl = (int)((p >> 17) & 127);
        atomicAdd(&acc[dl * 17 + c], dinv[s] * A[s * N_CLASSES + c]);
    }
    __syncthreads();
    int n0 = b * 128;
    for (int i = t; i < 128 * 16; i += 256) {
        int dl = i >> 4, cc = i & 15;
        int n = n0 + dl;
        if (n < N_NODES) {
            float dn = dinv[n];
            B[n * N_CLASSES + cc] = dn * acc[dl * 17 + cc] + dn * dn * A[n * N_CLASSES + cc];
        }
    }
}

// ---------- fused pool + bias + log_softmax ----------

__device__ __forceinline__ int lower_bound(const int* __restrict__ a, int n, int key) {
    int lo = 0, hi = n;
    while (lo < hi) {
        int m = (lo + hi) >> 1;
        if (a[m] < key) lo = m + 1; else hi = m;
    }
    return lo;
}

__global__ void pool_lsm_kernel(const float* __restrict__ y, const int* __restrict__ batch,
                                const float* __restrict__ b, float* __restrict__ out) {
    int g = blockIdx.x;
    int beg = lower_bound(batch, N_NODES, g);
    int end = lower_bound(batch, N_NODES, g + 1);
    int t = threadIdx.x;
    int slot = t >> 4, c = t & 15;
    float acc = 0.0f;
    for (int n = beg + slot; n < end; n += 16) acc += y[n * N_CLASSES + c];
    __shared__ float red[16][16];
    red[slot][c] = acc;
    __syncthreads();
    for (int s = 8; s >= 1; s >>= 1) {
        if (slot < s) red[slot][c] += red[slot + s][c];
        __syncthreads();
    }
    if (t < 16) {
        int cnt = end - beg;
        float v = (cnt > 0) ? red[0][t] / (float)cnt + b[t] : 0.0f;
        float m = v;
        for (int mask = 1; mask < 16; mask <<= 1) m = fmaxf(m, __shfl_xor(m, mask, 64));
        float s2 = expf(v - m);
        for (int mask = 1; mask < 16; mask <<= 1) s2 += __shfl_xor(s2, mask, 64);
        out[g * N_CLASSES + t] = v - m - logf(s2);
    }
}

extern "C" void kernel_launch(void* const* d_in, const int* in_sizes, int n_in,
                              void* d_out, int out_size, void* d_ws, size_t ws_size,
                              hipStream_t stream) {
    const float* x     = (const float*)d_in[0];
    const float* W     = (const float*)d_in[1];
    const float* b     = (const float*)d_in[2];
    const int*   ei    = (const int*)d_in[3];
    const int*   batch = (const int*)d_in[4];
    float*       out   = (float*)d_out;

    const int* src = ei;
    const int* dst = ei + N_EDGES;

    char* ws = (char*)d_ws;
    int*   hist    = (int*)(ws + 0x000000);    // 1024*782*4 = 3.2 MB
    int*   offs    = (int*)(ws + 0x320000);    // 782*1024*4 = 3.2 MB
    int*   total   = (int*)(ws + 0x640000);    // 3.1 KB
    int*   binbase = (int*)(ws + 0x642000);    // 3.1 KB
    int*   deg     = (int*)(ws + 0x650000);    // 400 KB
    float* dinv    = (float*)(ws + 0x6C0000);  // 400 KB
    unsigned int* bins = (unsigned int*)(ws + 0x740000);  // 12.8 MB
    float* yA      = (float*)(ws + 0x1400000); // 6.4 MB
    float* yB      = (float*)(ws + 0x1B00000); // 6.4 MB

    binhist_kernel<<<NBLK_A, 256, 0, stream>>>(dst, hist);
    offs_scan_kernel<<<NB, 1024, 0, stream>>>(hist, offs, total);
    total_scan_kernel<<<1, 1024, 0, stream>>>(total, binbase);
    binscatter_kernel<<<NBLK_A, 256, 0, stream>>>(src, dst, offs, binbase, bins);
    bindeg_kernel<<<NB, 256, 0, stream>>>(bins, binbase, total, deg);
    finalize_dinv_kernel<<<(N_NODES + 255) / 256, 256, 0, stream>>>(deg, dinv);

    xw_kernel<<<(N_NODES + 15) / 16, 256, 0, stream>>>(x, W, yA);

    hopbin_kernel<<<NB, 256, 0, stream>>>(bins, binbase, total, dinv, yA, yB);
    hopbin_kernel<<<NB, 256, 0, stream>>>(bins, binbase, total, dinv, yB, yA);
    hopbin_kernel<<<NB, 256, 0, stream>>>(bins, binbase, total, dinv, yA, yB);

    pool_lsm_kernel<<<NUM_GRAPHS, 256, 0, stream>>>(yB, batch, b, out);
}

// Round 8
// 322.972 us; speedup vs baseline: 3.7469x; 3.7469x over previous
//
#include <hip/hip_runtime.h>
#include <math.h>

#define N_NODES    100000
#define N_EDGES    3200000
#define N_FEAT     128
#define N_CLASSES  16
#define NUM_GRAPHS 512
#define NB         782          // bins of 128 nodes: bin = dst>>7 (782*128 = 100096)
#define NBLK_A     1024         // blocks in binning passes
#define EPB        3125         // edges per block: 1024*3125 = 3.2M exactly
#define SCAN_BLOCKS ((N_NODES + 255) / 256)   // 391

// ---------- pass A0: per-block coarse histogram ----------

__global__ void binhist_kernel(const int* __restrict__ dst, int* __restrict__ hist) {
    __shared__ int h[NB];
    int t = threadIdx.x;
    for (int i = t; i < NB; i += 256) h[i] = 0;
    __syncthreads();
    int base = blockIdx.x * EPB;
    for (int e = base + t; e < base + EPB; e += 256) atomicAdd(&h[dst[e] >> 7], 1);
    __syncthreads();
    for (int i = t; i < NB; i += 256) hist[blockIdx.x * NB + i] = h[i];
}

// ---------- per-bin scan over blocks -> offs[bin][block], total[bin] ----------

__global__ void offs_scan_kernel(const int* __restrict__ hist, int* __restrict__ offs,
                                 int* __restrict__ total) {
    __shared__ int v[1024];
    int b = blockIdx.x, t = threadIdx.x;   // 1024 threads
    int x = hist[t * NB + b];
    v[t] = x;
    __syncthreads();
    for (int off = 1; off < 1024; off <<= 1) {
        int a = (t >= off) ? v[t - off] : 0;
        __syncthreads();
        v[t] += a;
        __syncthreads();
    }
    offs[b * NBLK_A + t] = v[t] - x;
    if (t == 1023) total[b] = v[1023];
}

// ---------- scan of bin totals -> binbase ----------

__global__ void total_scan_kernel(const int* __restrict__ total, int* __restrict__ binbase) {
    __shared__ int v[1024];
    int t = threadIdx.x;
    int x = (t < NB) ? total[t] : 0;
    v[t] = x;
    __syncthreads();
    for (int off = 1; off < 1024; off <<= 1) {
        int a = (t >= off) ? v[t - off] : 0;
        __syncthreads();
        v[t] += a;
        __syncthreads();
    }
    if (t < NB) binbase[t] = v[t] - x;
}

// ---------- pass A1: local counting sort by bin (hist row reused), coalesced scatter ----------

__global__ void binscatter_kernel(const int* __restrict__ src, const int* __restrict__ dst,
                                  const int* __restrict__ hist,
                                  const int* __restrict__ offs, const int* __restrict__ binbase,
                                  unsigned int* __restrict__ bins) {
    __shared__ int h[NB];                    // counts -> cursor (3.1 KB)
    __shared__ int lstart[NB];               // 3.1 KB
    __shared__ int gstart[NB];               // 3.1 KB
    __shared__ int sv[256];                  // 1 KB
    __shared__ unsigned int outp[EPB];       // 12.5 KB
    __shared__ unsigned short binof[EPB];    // 6.25 KB
    int t = threadIdx.x, blk = blockIdx.x;
    for (int i = t; i < NB; i += 256) h[i] = hist[blk * NB + i];   // coalesced re-read
    __syncthreads();
    // exclusive scan of h[0..NB) : 4 bins per thread
    int b0 = 4 * t;
    int l0 = (b0 + 0 < NB) ? h[b0 + 0] : 0;
    int l1 = (b0 + 1 < NB) ? h[b0 + 1] : 0;
    int l2 = (b0 + 2 < NB) ? h[b0 + 2] : 0;
    int l3 = (b0 + 3 < NB) ? h[b0 + 3] : 0;
    int tsum = l0 + l1 + l2 + l3;
    sv[t] = tsum;
    __syncthreads();
    for (int off = 1; off < 256; off <<= 1) {
        int a = (t >= off) ? sv[t - off] : 0;
        __syncthreads();
        sv[t] += a;
        __syncthreads();
    }
    int ex = sv[t] - tsum;
    if (b0 + 0 < NB) lstart[b0 + 0] = ex;
    if (b0 + 1 < NB) lstart[b0 + 1] = ex + l0;
    if (b0 + 2 < NB) lstart[b0 + 2] = ex + l0 + l1;
    if (b0 + 3 < NB) lstart[b0 + 3] = ex + l0 + l1 + l2;
    __syncthreads();
    for (int i = t; i < NB; i += 256) {
        gstart[i] = offs[i * NBLK_A + blk] + binbase[i];
        h[i] = lstart[i];                    // cursor
    }
    __syncthreads();
    int base = blk * EPB;
    for (int e = base + t; e < base + EPB; e += 256) {
        int s = src[e], d = dst[e];
        int b = d >> 7;
        int pos = atomicAdd(&h[b], 1);
        outp[pos] = (unsigned int)s | ((unsigned int)(d & 127) << 17);
        binof[pos] = (unsigned short)b;
    }
    __syncthreads();
    for (int i = t; i < EPB; i += 256) {
        int b = binof[i];
        bins[gstart[b] + (i - lstart[b])] = outp[i];
    }
}

// ---------- per-bin node histogram -> deg ----------

__global__ void bindeg_kernel(const unsigned int* __restrict__ bins,
                              const int* __restrict__ binbase, const int* __restrict__ total,
                              int* __restrict__ deg) {
    __shared__ int h[128];
    int b = blockIdx.x, t = threadIdx.x;
    if (t < 128) h[t] = 0;
    __syncthreads();
    int base = binbase[b], cnt = total[b];
    for (int i = t; i < cnt; i += 256) atomicAdd(&h[(bins[base + i] >> 17) & 127], 1);
    __syncthreads();
    if (t < 128) {
        int node = b * 128 + t;
        if (node < N_NODES) deg[node] = h[t];
    }
}

// ---------- exclusive scan of deg -> rowp ----------

__global__ void scan1_kernel(const int* __restrict__ deg, int* __restrict__ row,
                             int* __restrict__ bsum) {
    __shared__ int tmp[256];
    int t = threadIdx.x;
    int i = blockIdx.x * 256 + t;
    int v = (i < N_NODES) ? deg[i] : 0;
    tmp[t] = v;
    __syncthreads();
    for (int off = 1; off < 256; off <<= 1) {
        int a = (t >= off) ? tmp[t - off] : 0;
        __syncthreads();
        tmp[t] += a;
        __syncthreads();
    }
    if (i < N_NODES) row[i] = tmp[t] - v;
    if (t == 255) bsum[blockIdx.x] = tmp[255];
}

__global__ void scan2_kernel(const int* __restrict__ bsum, int* __restrict__ boff) {
    __shared__ int tmp[512];
    int t = threadIdx.x;
    int v = (t < SCAN_BLOCKS) ? bsum[t] : 0;
    tmp[t] = v;
    __syncthreads();
    for (int off = 1; off < 512; off <<= 1) {
        int a = (t >= off) ? tmp[t - off] : 0;
        __syncthreads();
        tmp[t] += a;
        __syncthreads();
    }
    if (t < SCAN_BLOCKS) boff[t] = tmp[t] - v;
}

__global__ void scan3_kernel(int* __restrict__ row, const int* __restrict__ boff) {
    int i = blockIdx.x * 256 + threadIdx.x;
    if (i < N_NODES) row[i] += boff[blockIdx.x];
    if (i == 0) row[N_NODES] = N_EDGES;
}

__global__ void finalize_dinv_kernel(const int* __restrict__ deg, float* __restrict__ dinv) {
    int i = blockIdx.x * blockDim.x + threadIdx.x;
    if (i < N_NODES) dinv[i] = rsqrtf((float)(deg[i] + 1));
}

// ---------- per-bin counting sort by node -> exact CSR (coalesced) ----------

__global__ void binsort_kernel(const unsigned int* __restrict__ bins,
                               const int* __restrict__ binbase, const int* __restrict__ total,
                               const int* __restrict__ row, int* __restrict__ csr) {
    __shared__ int h[128], sv[128], cur[128];
    __shared__ int outs[5120];   // 20 KB; bin cnt ~4092 +- 64, 16 sigma margin
    int b = blockIdx.x, t = threadIdx.x;
    if (t < 128) h[t] = 0;
    __syncthreads();
    int base = binbase[b], cnt = total[b];
    for (int i = t; i < cnt; i += 256) atomicAdd(&h[(bins[base + i] >> 17) & 127], 1);
    __syncthreads();
    if (t < 128) sv[t] = h[t];
    __syncthreads();
    for (int off = 1; off < 128; off <<= 1) {
        int a = 0;
        if (t < 128 && t >= off) a = sv[t - off];
        __syncthreads();
        if (t < 128) sv[t] += a;
        __syncthreads();
    }
    if (t < 128) cur[t] = sv[t] - h[t];
    __syncthreads();
    for (int i = t; i < cnt; i += 256) {
        unsigned int p = bins[base + i];
        int pos = atomicAdd(&cur[(p >> 17) & 127], 1);
        outs[pos] = (int)(p & 0x1FFFF);
    }
    __syncthreads();
    int rb = row[b * 128];   // broadcast
    for (int i = t; i < cnt; i += 256) csr[rb + i] = outs[i];
}

// ---------- z0 = dinv * (x @ W) ----------

__global__ void xw_kernel(const float* __restrict__ x, const float* __restrict__ W,
                          const float* __restrict__ dinv, float* __restrict__ z) {
    __shared__ __align__(16) float sW[N_FEAT * N_CLASSES];   // 8 KB
    __shared__ __align__(16) float sx[16][132];              // padded
    int t = threadIdx.x;
    for (int i = t; i < (N_FEAT * N_CLASSES) / 4; i += 256)
        *(float4*)&sW[i * 4] = *(const float4*)&W[i * 4];
    int row0 = blockIdx.x * 16;
    for (int i = t; i < 16 * 32; i += 256) {
        int r = i >> 5, q = i & 31;
        int rr = row0 + r;
        float4 v = make_float4(0.f, 0.f, 0.f, 0.f);
        if (rr < N_NODES) v = *(const float4*)&x[(long long)rr * N_FEAT + q * 4];
        *(float4*)&sx[r][q * 4] = v;
    }
    __syncthreads();
    int r = t >> 4, c = t & 15;
    float acc = 0.0f;
#pragma unroll 8
    for (int k = 0; k < N_FEAT; ++k) acc += sx[r][k] * sW[k * N_CLASSES + c];
    int rr = row0 + r;
    if (rr < N_NODES) z[rr * N_CLASSES + c] = dinv[rr] * acc;
}

// ---------- node-parallel gather hop in z-space, unroll 4 ----------
// z'[n] = dn^2 * (sum_{s in N(n)} z[s] + z[n]);  last hop: dn^1 (emits y)

__global__ void hop_kernel(const int* __restrict__ row, const int* __restrict__ csr,
                           const float* __restrict__ dinv,
                           const float* __restrict__ Z, float* __restrict__ O, int last) {
    int n = blockIdx.x * 16 + (threadIdx.x >> 4);
    int c = threadIdx.x & 15;
    if (n >= N_NODES) return;
    int beg = row[n], end = row[n + 1];
    float acc = 0.0f;
    int j = beg;
    for (; j + 4 <= end; j += 4) {
        int s0 = csr[j], s1 = csr[j + 1], s2 = csr[j + 2], s3 = csr[j + 3];
        float a0 = Z[s0 * N_CLASSES + c];
        float a1 = Z[s1 * N_CLASSES + c];
        float a2 = Z[s2 * N_CLASSES + c];
        float a3 = Z[s3 * N_CLASSES + c];
        acc += (a0 + a1) + (a2 + a3);
    }
    for (; j < end; ++j) acc += Z[csr[j] * N_CLASSES + c];
    float dn = dinv[n];
    float scale = last ? dn : dn * dn;
    O[n * N_CLASSES + c] = scale * (acc + Z[n * N_CLASSES + c]);
}

// ---------- fused pool + bias + log_softmax ----------

__device__ __forceinline__ int lower_bound(const int* __restrict__ a, int n, int key) {
    int lo = 0, hi = n;
    while (lo < hi) {
        int m = (lo + hi) >> 1;
        if (a[m] < key) lo = m + 1; else hi = m;
    }
    return lo;
}

__global__ void pool_lsm_kernel(const float* __restrict__ y, const int* __restrict__ batch,
                                const float* __restrict__ b, float* __restrict__ out) {
    int g = blockIdx.x;
    int beg = lower_bound(batch, N_NODES, g);
    int end = lower_bound(batch, N_NODES, g + 1);
    int t = threadIdx.x;
    int slot = t >> 4, c = t & 15;
    float acc = 0.0f;
    for (int n = beg + slot; n < end; n += 16) acc += y[n * N_CLASSES + c];
    __shared__ float red[16][16];
    red[slot][c] = acc;
    __syncthreads();
    for (int s = 8; s >= 1; s >>= 1) {
        if (slot < s) red[slot][c] += red[slot + s][c];
        __syncthreads();
    }
    if (t < 16) {
        int cnt = end - beg;
        float v = (cnt > 0) ? red[0][t] / (float)cnt + b[t] : 0.0f;
        float m = v;
        for (int mask = 1; mask < 16; mask <<= 1) m = fmaxf(m, __shfl_xor(m, mask, 64));
        float s2 = expf(v - m);
        for (int mask = 1; mask < 16; mask <<= 1) s2 += __shfl_xor(s2, mask, 64);
        out[g * N_CLASSES + t] = v - m - logf(s2);
    }
}

extern "C" void kernel_launch(void* const* d_in, const int* in_sizes, int n_in,
                              void* d_out, int out_size, void* d_ws, size_t ws_size,
                              hipStream_t stream) {
    const float* x     = (const float*)d_in[0];
    const float* W     = (const float*)d_in[1];
    const float* b     = (const float*)d_in[2];
    const int*   ei    = (const int*)d_in[3];
    const int*   batch = (const int*)d_in[4];
    float*       out   = (float*)d_out;

    const int* src = ei;
    const int* dst = ei + N_EDGES;

    char* ws = (char*)d_ws;
    int*   hist    = (int*)(ws + 0x000000);    // 1024*782*4 = 0x30E000
    int*   offs    = (int*)(ws + 0x30E000);    // 782*1024*4 = 0x30E000
    int*   total   = (int*)(ws + 0x61C000);    // 3.1 KB
    int*   binbase = (int*)(ws + 0x61D000);    // 3.1 KB
    int*   bsum    = (int*)(ws + 0x61E000);    // 1.6 KB
    int*   boff    = (int*)(ws + 0x61F000);    // 1.6 KB
    int*   deg     = (int*)(ws + 0x620000);    // 400 KB
    float* dinv    = (float*)(ws + 0x682000);  // 400 KB
    int*   rowp    = (int*)(ws + 0x6E4000);    // 400 KB + 4
    unsigned int* bins = (unsigned int*)(ws + 0x746000);  // 12.8 MB
    int*   csr     = (int*)(ws + 0x137B000);   // 12.8 MB
    float* zA      = (float*)(ws + 0x1FB0000); // 6.4 MB
    float* zB      = (float*)(ws + 0x25CB000); // 6.4 MB  (ends ~43.9 MB)

    binhist_kernel<<<NBLK_A, 256, 0, stream>>>(dst, hist);
    offs_scan_kernel<<<NB, 1024, 0, stream>>>(hist, offs, total);
    total_scan_kernel<<<1, 1024, 0, stream>>>(total, binbase);
    binscatter_kernel<<<NBLK_A, 256, 0, stream>>>(src, dst, hist, offs, binbase, bins);
    bindeg_kernel<<<NB, 256, 0, stream>>>(bins, binbase, total, deg);
    scan1_kernel<<<SCAN_BLOCKS, 256, 0, stream>>>(deg, rowp, bsum);
    scan2_kernel<<<1, 512, 0, stream>>>(bsum, boff);
    scan3_kernel<<<SCAN_BLOCKS, 256, 0, stream>>>(rowp, boff);
    finalize_dinv_kernel<<<SCAN_BLOCKS, 256, 0, stream>>>(deg, dinv);
    binsort_kernel<<<NB, 256, 0, stream>>>(bins, binbase, total, rowp, csr);

    xw_kernel<<<(N_NODES + 15) / 16, 256, 0, stream>>>(x, W, dinv, zA);

    hop_kernel<<<(N_NODES + 15) / 16, 256, 0, stream>>>(rowp, csr, dinv, zA, zB, 0);
    hop_kernel<<<(N_NODES + 15) / 16, 256, 0, stream>>>(rowp, csr, dinv, zB, zA, 0);
    hop_kernel<<<(N_NODES + 15) / 16, 256, 0, stream>>>(rowp, csr, dinv, zA, zB, 1);

    pool_lsm_kernel<<<NUM_GRAPHS, 256, 0, stream>>>(zB, batch, b, out);
}